// Round 3
// baseline (953.044 us; speedup 1.0000x reference)
//
#include <hip/hip_runtime.h>
#include <stdint.h>

#define N_NODES 100000
#define N_EDGES 1600000
#define IN_DIM 32
#define OUT_DIM 64
#define N_REL 8
#define EPS 1e-10f

static __device__ __forceinline__ float bflo(uint32_t u) { return __uint_as_float(u << 16); }
static __device__ __forceinline__ float bfhi(uint32_t u) { return __uint_as_float(u & 0xffff0000u); }
static __device__ __forceinline__ uint16_t f2bf(float f) {
    uint32_t u = __float_as_uint(f);
    return (uint16_t)((u + 0x7fffu + ((u >> 16) & 1u)) >> 16); // RNE
}

// ---------------------------------------------------------------------------
// Dtype probe: x ~ N(0,1). If bf16 pairs, low-half exponent field <= ~131.
// If fp32, low 16 bits are random mantissa bits -> exponent field uniform,
// ~37% >= 160. Count over 4096 dwords (16KB, safe for either dtype).
// ---------------------------------------------------------------------------
__global__ __launch_bounds__(256) void detect_kernel(const uint32_t* __restrict__ xw,
                                                     int* __restrict__ flag) {
    __shared__ int cnt;
    if (threadIdx.x == 0) cnt = 0;
    __syncthreads();
    int c = 0;
    for (int k = threadIdx.x; k < 4096; k += 256) {
        uint32_t w = xw[k];
        uint32_t e = (w >> 7) & 0xffu;   // exponent of low half viewed as bf16
        c += (e >= 160u) ? 1 : 0;
    }
    atomicAdd(&cnt, c);
    __syncthreads();
    if (threadIdx.x == 0) *flag = (cnt > 64) ? 1 : 0;  // 1 = fp32 inputs
}

// ---------------------------------------------------------------------------
// den[dst*8+rel] += w
// ---------------------------------------------------------------------------
__global__ __launch_bounds__(256) void den_kernel(const int* __restrict__ el,
                                                  const void* __restrict__ ew,
                                                  const int* __restrict__ flag,
                                                  float* __restrict__ den) {
    int e = blockIdx.x * 256 + threadIdx.x;
    if (e >= N_EDGES) return;
    int dst = el[e * 3 + 1];
    int rel = el[e * 3 + 2];
    float w = (*flag) ? ((const float*)ew)[e]
                      : bflo((uint32_t)((const uint16_t*)ew)[e]);
    atomicAdd(&den[dst * N_REL + rel], w);
}

// ---------------------------------------------------------------------------
// Per edge (one wave, lane = output channel):
//   acc[dst,o] += (w/(den[dst,rel]+eps)) * sum_i x[src,i] * Wl[rel*32+i, o]
// Wl staged in LDS as fp32 (64KB). Grid-stride so staging is amortized.
// ---------------------------------------------------------------------------
__global__ __launch_bounds__(256) void edge_mm_kernel(const int* __restrict__ el,
                                                      const void* __restrict__ ew,
                                                      const void* __restrict__ x,
                                                      const void* __restrict__ Wl,
                                                      const float* __restrict__ den,
                                                      const int* __restrict__ flag,
                                                      float* __restrict__ acc) {
    __shared__ float sW[N_REL * IN_DIM * OUT_DIM]; // 16384 f32 = 64KB
    int f32 = *flag;

    if (f32) {
        const float* W = (const float*)Wl;
        for (int k = threadIdx.x; k < N_REL * IN_DIM * OUT_DIM; k += 256) sW[k] = W[k];
    } else {
        const uint16_t* W = (const uint16_t*)Wl;
        for (int k = threadIdx.x; k < N_REL * IN_DIM * OUT_DIM; k += 256)
            sW[k] = bflo((uint32_t)W[k]);
    }
    __syncthreads();

    int lane = threadIdx.x & 63;
    int wv   = threadIdx.x >> 6;

    for (int e = blockIdx.x * 4 + wv; e < N_EDGES; e += gridDim.x * 4) {
        int src = el[e * 3 + 0];
        int dst = el[e * 3 + 1];
        int rel = el[e * 3 + 2];
        float w = f32 ? ((const float*)ew)[e]
                      : bflo((uint32_t)((const uint16_t*)ew)[e]);
        float scale = w / (den[dst * N_REL + rel] + EPS);

        float y = 0.0f;
        if (f32) {
            const float4* xr = (const float4*)((const float*)x + (size_t)src * IN_DIM);
            #pragma unroll
            for (int q = 0; q < 8; ++q) {
                float4 v = xr[q];
                int base = (rel * IN_DIM + q * 4) * OUT_DIM + lane;
                y += v.x * sW[base]
                   + v.y * sW[base + OUT_DIM]
                   + v.z * sW[base + 2 * OUT_DIM]
                   + v.w * sW[base + 3 * OUT_DIM];
            }
        } else {
            const uint32_t* xr = (const uint32_t*)((const uint16_t*)x + (size_t)src * IN_DIM);
            #pragma unroll
            for (int q = 0; q < 16; ++q) {
                uint32_t p = xr[q];
                int base = (rel * IN_DIM + q * 2) * OUT_DIM + lane;
                y += bflo(p) * sW[base] + bfhi(p) * sW[base + OUT_DIM];
            }
        }
        atomicAdd(&acc[(size_t)dst * OUT_DIM + lane], y * scale);
    }
}

// ---------------------------------------------------------------------------
// out[n,o] = relu(acc[n,o] + sum_i x[n,i]*Ws[i,o] + bl[o] + bs[o])
// ---------------------------------------------------------------------------
__global__ __launch_bounds__(256) void finalize_kernel(const float* __restrict__ acc,
                                                       const void* __restrict__ x,
                                                       const void* __restrict__ Ws,
                                                       const void* __restrict__ bl,
                                                       const void* __restrict__ bs,
                                                       const int* __restrict__ flag,
                                                       void* __restrict__ out) {
    __shared__ float sW[IN_DIM * OUT_DIM]; // 2048 f32 = 8KB
    int f32 = *flag;

    if (f32) {
        const float* W = (const float*)Ws;
        for (int k = threadIdx.x; k < IN_DIM * OUT_DIM; k += 256) sW[k] = W[k];
    } else {
        const uint16_t* W = (const uint16_t*)Ws;
        for (int k = threadIdx.x; k < IN_DIM * OUT_DIM; k += 256) sW[k] = bflo((uint32_t)W[k]);
    }
    __syncthreads();

    int wave = (int)(((long long)blockIdx.x * 256 + threadIdx.x) >> 6);
    int lane = threadIdx.x & 63;
    if (wave >= N_NODES) return;
    int n = wave;

    float a = acc[(size_t)n * OUT_DIM + lane];
    if (f32) {
        a += ((const float*)bl)[lane] + ((const float*)bs)[lane];
        const float4* xr = (const float4*)((const float*)x + (size_t)n * IN_DIM);
        #pragma unroll
        for (int q = 0; q < 8; ++q) {
            float4 v = xr[q];
            int base = (q * 4) * OUT_DIM + lane;
            a += v.x * sW[base]
               + v.y * sW[base + OUT_DIM]
               + v.z * sW[base + 2 * OUT_DIM]
               + v.w * sW[base + 3 * OUT_DIM];
        }
    } else {
        a += bflo((uint32_t)((const uint16_t*)bl)[lane])
           + bflo((uint32_t)((const uint16_t*)bs)[lane]);
        const uint32_t* xr = (const uint32_t*)((const uint16_t*)x + (size_t)n * IN_DIM);
        #pragma unroll
        for (int q = 0; q < 16; ++q) {
            uint32_t p = xr[q];
            int base = (q * 2) * OUT_DIM + lane;
            a += bflo(p) * sW[base] + bfhi(p) * sW[base + OUT_DIM];
        }
    }

    a = fmaxf(a, 0.0f);
    if (f32) ((float*)out)[(size_t)n * OUT_DIM + lane] = a;
    else     ((uint16_t*)out)[(size_t)n * OUT_DIM + lane] = f2bf(a);
}

// ===========================================================================
extern "C" void kernel_launch(void* const* d_in, const int* in_sizes, int n_in,
                              void* d_out, int out_size, void* d_ws, size_t ws_size,
                              hipStream_t stream) {
    const void* x  = d_in[0];
    const int* el  = (const int*)d_in[1];
    const void* ew = d_in[2];
    const void* Wl = d_in[3];
    const void* bl = d_in[4];
    const void* Ws = d_in[5];
    const void* bs = d_in[6];

    const size_t DEN_ELEMS = (size_t)N_NODES * N_REL;    // 0.8M
    const size_t ACC_ELEMS = (size_t)N_NODES * OUT_DIM;  // 6.4M
    // layout: [flag pad 64B][den 3.2MB][acc 25.6MB]
    const size_t REQ = 64 + (DEN_ELEMS + ACC_ELEMS) * sizeof(float);
    if (ws_size < REQ) return; // diagnostic: absmax ~= max|ref| => ws too small

    int*   flag = (int*)d_ws;
    float* den  = (float*)((char*)d_ws + 64);
    float* acc  = den + DEN_ELEMS;

    hipMemsetAsync(d_ws, 0, REQ, stream);
    detect_kernel<<<1, 256, 0, stream>>>((const uint32_t*)x, flag);
    den_kernel<<<(N_EDGES + 255) / 256, 256, 0, stream>>>(el, ew, flag, den);
    edge_mm_kernel<<<2048, 256, 0, stream>>>(el, ew, x, Wl, den, flag, acc);
    {
        long long threads = (long long)N_NODES * 64;
        int blocks = (int)((threads + 255) / 256);
        finalize_kernel<<<blocks, 256, 0, stream>>>(acc, x, Ws, bl, bs, flag, d_out);
    }
}

// Round 4
// 660.298 us; speedup vs baseline: 1.4434x; 1.4434x over previous
//
#include <hip/hip_runtime.h>
#include <stdint.h>

#define N_NODES 100000
#define N_EDGES 1600000
#define IN_DIM 32
#define OUT_DIM 64
#define N_REL 8
#define EPS 1e-10f

static __device__ __forceinline__ float bflo(uint32_t u) { return __uint_as_float(u << 16); }
static __device__ __forceinline__ float bfhi(uint32_t u) { return __uint_as_float(u & 0xffff0000u); }
static __device__ __forceinline__ uint16_t f2bf(float f) {
    uint32_t u = __float_as_uint(f);
    return (uint16_t)((u + 0x7fffu + ((u >> 16) & 1u)) >> 16); // RNE
}

// ---------------------------------------------------------------------------
// Dtype probe (kept from round 2 — proved inputs are fp32, costs ~5us).
// ---------------------------------------------------------------------------
__global__ __launch_bounds__(256) void detect_kernel(const uint32_t* __restrict__ xw,
                                                     int* __restrict__ flag) {
    __shared__ int cnt;
    if (threadIdx.x == 0) cnt = 0;
    __syncthreads();
    int c = 0;
    for (int k = threadIdx.x; k < 4096; k += 256) {
        uint32_t w = xw[k];
        uint32_t e = (w >> 7) & 0xffu;
        c += (e >= 160u) ? 1 : 0;
    }
    atomicAdd(&cnt, c);
    __syncthreads();
    if (threadIdx.x == 0) *flag = (cnt > 64) ? 1 : 0;  // 1 = fp32 inputs
}

// ===========================================================================
// PATH A: scatter num/den (32 lanes per edge, coalesced atomics, no LDS)
// ===========================================================================
__global__ __launch_bounds__(256) void scatter_kernel(
    const int* __restrict__ el,
    const void* __restrict__ ew,
    const void* __restrict__ x,
    const int* __restrict__ flag,
    float* __restrict__ num,
    float* __restrict__ den)
{
    long long t = (long long)blockIdx.x * 256 + threadIdx.x;
    int e = (int)(t >> 5);
    int i = (int)(t & 31);
    if (e >= N_EDGES) return;

    int src = el[e * 3 + 0];
    int dst = el[e * 3 + 1];
    int rel = el[e * 3 + 2];
    int f32 = *flag;

    float w  = f32 ? ((const float*)ew)[e]
                   : bflo((uint32_t)((const uint16_t*)ew)[e]);
    float xv = f32 ? ((const float*)x)[(size_t)src * IN_DIM + i]
                   : bflo((uint32_t)((const uint16_t*)x)[(size_t)src * IN_DIM + i]);
    int seg = dst * N_REL + rel;

    atomicAdd(&num[(size_t)seg * IN_DIM + i], w * xv);
    if (i == 0) atomicAdd(&den[seg], w);
}

// ---------------------------------------------------------------------------
// PATH A dense: one wave per node, lane = out channel. Wl in 64KB LDS.
// out[n,o] = relu( sum_r (sum_i num[n,r,i]*Wl[r*32+i,o]) / (den[n,r]+eps)
//                  + sum_i x[n,i]*Ws[i,o] + bl[o] + bs[o] )
// ---------------------------------------------------------------------------
__global__ __launch_bounds__(256) void dense_kernel(
    const float* __restrict__ num,
    const float* __restrict__ den,
    const void* __restrict__ x,
    const void* __restrict__ Wl,
    const void* __restrict__ bl,
    const void* __restrict__ Ws,
    const void* __restrict__ bs,
    const int* __restrict__ flag,
    void* __restrict__ out)
{
    __shared__ float sW[N_REL * IN_DIM * OUT_DIM]; // 16384 f32 = 64KB
    int f32 = *flag;

    if (f32) {
        const float* W = (const float*)Wl;
        for (int k = threadIdx.x; k < N_REL * IN_DIM * OUT_DIM; k += 256) sW[k] = W[k];
    } else {
        const uint16_t* W = (const uint16_t*)Wl;
        for (int k = threadIdx.x; k < N_REL * IN_DIM * OUT_DIM; k += 256)
            sW[k] = bflo((uint32_t)W[k]);
    }
    __syncthreads();

    int wave = (int)(((long long)blockIdx.x * 256 + threadIdx.x) >> 6);
    int lane = threadIdx.x & 63;
    if (wave >= N_NODES) return;
    int n = wave;

    float acc;
    if (f32) acc = ((const float*)bl)[lane] + ((const float*)bs)[lane];
    else     acc = bflo((uint32_t)((const uint16_t*)bl)[lane])
                 + bflo((uint32_t)((const uint16_t*)bs)[lane]);

    // relation part: partial sum per relation, then one divide
    const float4* nr = (const float4*)(num + (size_t)n * (N_REL * IN_DIM));
    const float* denrow = den + (size_t)n * N_REL;
    #pragma unroll
    for (int r = 0; r < N_REL; ++r) {
        float accR = 0.0f;
        #pragma unroll
        for (int q = 0; q < IN_DIM / 4; ++q) {
            float4 v = nr[r * (IN_DIM / 4) + q];
            int base = (r * IN_DIM + q * 4) * OUT_DIM + lane;
            accR += v.x * sW[base]
                  + v.y * sW[base + OUT_DIM]
                  + v.z * sW[base + 2 * OUT_DIM]
                  + v.w * sW[base + 3 * OUT_DIM];
        }
        acc += accR / (denrow[r] + EPS);
    }

    // self connection (Ws from global: 8KB fp32, L1/L2-resident broadcast)
    if (f32) {
        const float* xr = (const float*)x + (size_t)n * IN_DIM;
        const float* W = (const float*)Ws;
        #pragma unroll
        for (int i = 0; i < IN_DIM; ++i)
            acc += xr[i] * W[i * OUT_DIM + lane];
    } else {
        const uint32_t* xr = (const uint32_t*)((const uint16_t*)x + (size_t)n * IN_DIM);
        const uint16_t* W = (const uint16_t*)Ws;
        #pragma unroll
        for (int ih = 0; ih < IN_DIM / 2; ++ih) {
            uint32_t p = xr[ih];
            acc += bflo(p) * bflo((uint32_t)W[(2 * ih) * OUT_DIM + lane])
                 + bfhi(p) * bflo((uint32_t)W[(2 * ih + 1) * OUT_DIM + lane]);
        }
    }

    acc = fmaxf(acc, 0.0f);
    if (f32) ((float*)out)[(size_t)n * OUT_DIM + lane] = acc;
    else     ((uint16_t*)out)[(size_t)n * OUT_DIM + lane] = f2bf(acc);
}

// ===========================================================================
// PATH B fallback (round-2 code, known good at 953us) — used if ws too small
// ===========================================================================
__global__ __launch_bounds__(256) void den_kernel(const int* __restrict__ el,
                                                  const void* __restrict__ ew,
                                                  const int* __restrict__ flag,
                                                  float* __restrict__ den) {
    int e = blockIdx.x * 256 + threadIdx.x;
    if (e >= N_EDGES) return;
    int dst = el[e * 3 + 1];
    int rel = el[e * 3 + 2];
    float w = (*flag) ? ((const float*)ew)[e]
                      : bflo((uint32_t)((const uint16_t*)ew)[e]);
    atomicAdd(&den[dst * N_REL + rel], w);
}

__global__ __launch_bounds__(256) void edge_mm_kernel(const int* __restrict__ el,
                                                      const void* __restrict__ ew,
                                                      const void* __restrict__ x,
                                                      const void* __restrict__ Wl,
                                                      const float* __restrict__ den,
                                                      const int* __restrict__ flag,
                                                      float* __restrict__ acc) {
    __shared__ float sW[N_REL * IN_DIM * OUT_DIM]; // 64KB
    int f32 = *flag;
    if (f32) {
        const float* W = (const float*)Wl;
        for (int k = threadIdx.x; k < N_REL * IN_DIM * OUT_DIM; k += 256) sW[k] = W[k];
    } else {
        const uint16_t* W = (const uint16_t*)Wl;
        for (int k = threadIdx.x; k < N_REL * IN_DIM * OUT_DIM; k += 256)
            sW[k] = bflo((uint32_t)W[k]);
    }
    __syncthreads();

    int lane = threadIdx.x & 63;
    int wv   = threadIdx.x >> 6;
    for (int e = blockIdx.x * 4 + wv; e < N_EDGES; e += gridDim.x * 4) {
        int src = el[e * 3 + 0];
        int dst = el[e * 3 + 1];
        int rel = el[e * 3 + 2];
        float w = f32 ? ((const float*)ew)[e]
                      : bflo((uint32_t)((const uint16_t*)ew)[e]);
        float scale = w / (den[dst * N_REL + rel] + EPS);
        float y = 0.0f;
        if (f32) {
            const float4* xr = (const float4*)((const float*)x + (size_t)src * IN_DIM);
            #pragma unroll
            for (int q = 0; q < 8; ++q) {
                float4 v = xr[q];
                int base = (rel * IN_DIM + q * 4) * OUT_DIM + lane;
                y += v.x * sW[base] + v.y * sW[base + OUT_DIM]
                   + v.z * sW[base + 2 * OUT_DIM] + v.w * sW[base + 3 * OUT_DIM];
            }
        } else {
            const uint32_t* xr = (const uint32_t*)((const uint16_t*)x + (size_t)src * IN_DIM);
            #pragma unroll
            for (int q = 0; q < 16; ++q) {
                uint32_t p = xr[q];
                int base = (rel * IN_DIM + q * 2) * OUT_DIM + lane;
                y += bflo(p) * sW[base] + bfhi(p) * sW[base + OUT_DIM];
            }
        }
        atomicAdd(&acc[(size_t)dst * OUT_DIM + lane], y * scale);
    }
}

__global__ __launch_bounds__(256) void finalize_kernel(const float* __restrict__ acc,
                                                       const void* __restrict__ x,
                                                       const void* __restrict__ Ws,
                                                       const void* __restrict__ bl,
                                                       const void* __restrict__ bs,
                                                       const int* __restrict__ flag,
                                                       void* __restrict__ out) {
    __shared__ float sW[IN_DIM * OUT_DIM]; // 8KB
    int f32 = *flag;
    if (f32) {
        const float* W = (const float*)Ws;
        for (int k = threadIdx.x; k < IN_DIM * OUT_DIM; k += 256) sW[k] = W[k];
    } else {
        const uint16_t* W = (const uint16_t*)Ws;
        for (int k = threadIdx.x; k < IN_DIM * OUT_DIM; k += 256) sW[k] = bflo((uint32_t)W[k]);
    }
    __syncthreads();

    int wave = (int)(((long long)blockIdx.x * 256 + threadIdx.x) >> 6);
    int lane = threadIdx.x & 63;
    if (wave >= N_NODES) return;
    int n = wave;

    float a = acc[(size_t)n * OUT_DIM + lane];
    if (f32) {
        a += ((const float*)bl)[lane] + ((const float*)bs)[lane];
        const float4* xr = (const float4*)((const float*)x + (size_t)n * IN_DIM);
        #pragma unroll
        for (int q = 0; q < 8; ++q) {
            float4 v = xr[q];
            int base = (q * 4) * OUT_DIM + lane;
            a += v.x * sW[base] + v.y * sW[base + OUT_DIM]
               + v.z * sW[base + 2 * OUT_DIM] + v.w * sW[base + 3 * OUT_DIM];
        }
    } else {
        a += bflo((uint32_t)((const uint16_t*)bl)[lane])
           + bflo((uint32_t)((const uint16_t*)bs)[lane]);
        const uint32_t* xr = (const uint32_t*)((const uint16_t*)x + (size_t)n * IN_DIM);
        #pragma unroll
        for (int q = 0; q < 16; ++q) {
            uint32_t p = xr[q];
            int base = (q * 2) * OUT_DIM + lane;
            a += bflo(p) * sW[base] + bfhi(p) * sW[base + OUT_DIM];
        }
    }
    a = fmaxf(a, 0.0f);
    if (f32) ((float*)out)[(size_t)n * OUT_DIM + lane] = a;
    else     ((uint16_t*)out)[(size_t)n * OUT_DIM + lane] = f2bf(a);
}

// ===========================================================================
extern "C" void kernel_launch(void* const* d_in, const int* in_sizes, int n_in,
                              void* d_out, int out_size, void* d_ws, size_t ws_size,
                              hipStream_t stream) {
    const void* x  = d_in[0];
    const int* el  = (const int*)d_in[1];
    const void* ew = d_in[2];
    const void* Wl = d_in[3];
    const void* bl = d_in[4];
    const void* Ws = d_in[5];
    const void* bs = d_in[6];

    const size_t DEN_ELEMS = (size_t)N_NODES * N_REL;            // 0.8M
    const size_t NUM_ELEMS = (size_t)N_NODES * N_REL * IN_DIM;   // 25.6M
    const size_t ACC_ELEMS = (size_t)N_NODES * OUT_DIM;          // 6.4M
    const size_t REQ_A = 64 + (DEN_ELEMS + NUM_ELEMS) * sizeof(float); // ~105.6MB
    const size_t REQ_B = 64 + (DEN_ELEMS + ACC_ELEMS) * sizeof(float); // ~28.8MB

    if (ws_size >= REQ_A) {
        int*   flag = (int*)d_ws;
        float* den  = (float*)((char*)d_ws + 64);
        float* num  = den + DEN_ELEMS;
        hipMemsetAsync(d_ws, 0, REQ_A, stream);
        detect_kernel<<<1, 256, 0, stream>>>((const uint32_t*)x, flag);
        {
            long long threads = (long long)N_EDGES * 32;
            int blocks = (int)((threads + 255) / 256);
            scatter_kernel<<<blocks, 256, 0, stream>>>(el, ew, x, flag, num, den);
        }
        {
            long long threads = (long long)N_NODES * 64;
            int blocks = (int)((threads + 255) / 256);
            dense_kernel<<<blocks, 256, 0, stream>>>(num, den, x, Wl, bl, Ws, bs, flag, d_out);
        }
    } else {
        if (ws_size < REQ_B) return;
        int*   flag = (int*)d_ws;
        float* den  = (float*)((char*)d_ws + 64);
        float* acc  = den + DEN_ELEMS;
        hipMemsetAsync(d_ws, 0, REQ_B, stream);
        detect_kernel<<<1, 256, 0, stream>>>((const uint32_t*)x, flag);
        den_kernel<<<(N_EDGES + 255) / 256, 256, 0, stream>>>(el, ew, flag, den);
        edge_mm_kernel<<<2048, 256, 0, stream>>>(el, ew, x, Wl, den, flag, acc);
        {
            long long threads = (long long)N_NODES * 64;
            int blocks = (int)((threads + 255) / 256);
            finalize_kernel<<<blocks, 256, 0, stream>>>(acc, x, Ws, bl, bs, flag, d_out);
        }
    }
}

// Round 5
// 415.563 us; speedup vs baseline: 2.2934x; 1.5889x over previous
//
#include <hip/hip_runtime.h>
#include <stdint.h>

#define N_NODES 100000
#define N_EDGES 1600000
#define IN_DIM 32
#define OUT_DIM 64
#define N_REL 8
#define EPS 1e-10f
#define K_TOT 288           // 8 rel * 32 + 32 self
#define N_KK 9              // K-tiles of 32

typedef __attribute__((ext_vector_type(8))) short bf16x8;
typedef __attribute__((ext_vector_type(4))) float f32x4;

static __device__ __forceinline__ float bflo(uint32_t u) { return __uint_as_float(u << 16); }
static __device__ __forceinline__ uint16_t f2bf(float f) {
    uint32_t u = __float_as_uint(f);
    return (uint16_t)((u + 0x7fffu + ((u >> 16) & 1u)) >> 16); // RNE
}

// ---------------------------------------------------------------------------
// Dtype probe (round-3 proved fp32; kept for safety, ~3us).
// ---------------------------------------------------------------------------
__global__ __launch_bounds__(256) void detect_kernel(const uint32_t* __restrict__ xw,
                                                     int* __restrict__ flag) {
    __shared__ int cnt;
    if (threadIdx.x == 0) cnt = 0;
    __syncthreads();
    int c = 0;
    for (int k = threadIdx.x; k < 4096; k += 256) {
        uint32_t w = xw[k];
        uint32_t e = (w >> 7) & 0xffu;
        c += (e >= 160u) ? 1 : 0;
    }
    atomicAdd(&cnt, c);
    __syncthreads();
    if (threadIdx.x == 0) *flag = (cnt > 64) ? 1 : 0;  // 1 = fp32 inputs
}

// ---------------------------------------------------------------------------
// Scatter: 32 lanes per edge -> num[seg*32+i] += w*x[src,i]; lane0 den += w.
// Coalesced 128B atomic bursts, no LDS -> full occupancy.
// ---------------------------------------------------------------------------
__global__ __launch_bounds__(256) void scatter_kernel(
    const int* __restrict__ el,
    const void* __restrict__ ew,
    const void* __restrict__ x,
    const int* __restrict__ flag,
    float* __restrict__ num,
    float* __restrict__ den)
{
    long long t = (long long)blockIdx.x * 256 + threadIdx.x;
    int e = (int)(t >> 5);
    int i = (int)(t & 31);
    if (e >= N_EDGES) return;

    int src = el[e * 3 + 0];
    int dst = el[e * 3 + 1];
    int rel = el[e * 3 + 2];
    int f32 = *flag;

    float w  = f32 ? ((const float*)ew)[e]
                   : bflo((uint32_t)((const uint16_t*)ew)[e]);
    float xv = f32 ? ((const float*)x)[(size_t)src * IN_DIM + i]
                   : bflo((uint32_t)((const uint16_t*)x)[(size_t)src * IN_DIM + i]);
    int seg = dst * N_REL + rel;

    atomicAdd(&num[(size_t)seg * IN_DIM + i], w * xv);
    if (i == 0) atomicAdd(&den[seg], w);
}

// ---------------------------------------------------------------------------
// Dense phase as MFMA GEMM: C[100000 x 64] = A[100000 x 288] * W[288 x 64]
//   A[n][r*32+i] = num[n][r][i] / (den[n][r]+eps)   (r<8)
//   A[n][256+i]  = x[n][i]                          (self)
// Block = 4 waves = 64 nodes; wave w -> nodes n0+16w..+15, all 64 outputs.
// K-tile kk (32 wide) == relation kk, so one inv per lane per K-step.
// W staged in LDS as bf16 pre-swizzled into b-frag order:
//   sB[kk][ot][lane][j] = W[kk*32 + (lane>>4)*8 + j][ot*16 + (lane&15)]
// -> per K-step per o-tile: one ds_read_b128.
// MFMA layouts (HW-verified, cdna_hip_programming §3):
//   A: a[j] = A[m=lane&15][k=quad*8+j]
//   B: b[j] = B[k=quad*8+j][n=lane&15]
//   C: c[reg] = C[row=quad*4+reg][col=lane&15]
// ---------------------------------------------------------------------------
__global__ __launch_bounds__(256) void dense_mfma_kernel(
    const float* __restrict__ num,
    const float* __restrict__ den,
    const void* __restrict__ x,
    const void* __restrict__ Wl,
    const void* __restrict__ bl,
    const void* __restrict__ Ws,
    const void* __restrict__ bs,
    const int* __restrict__ flag,
    void* __restrict__ out)
{
    __shared__ uint16_t sB[N_KK * 4 * 64 * 8]; // 18432 bf16 = 36KB
    int f32 = *flag;

    // ---- stage + swizzle W into LDS (once per block) ----
    for (int idx = threadIdx.x; idx < N_KK * 4 * 64 * 8; idx += 256) {
        int j    = idx & 7;
        int lane = (idx >> 3) & 63;
        int ot   = (idx >> 9) & 3;
        int kk   = idx >> 11;
        int quad = lane >> 4;
        int k = kk * 32 + quad * 8 + j;
        int o = ot * 16 + (lane & 15);
        if (f32) {
            float v = (k < 256) ? ((const float*)Wl)[(size_t)k * OUT_DIM + o]
                                : ((const float*)Ws)[(size_t)(k - 256) * OUT_DIM + o];
            sB[idx] = f2bf(v);
        } else {
            sB[idx] = (k < 256) ? ((const uint16_t*)Wl)[(size_t)k * OUT_DIM + o]
                                : ((const uint16_t*)Ws)[(size_t)(k - 256) * OUT_DIM + o];
        }
    }
    __syncthreads();

    int wid  = threadIdx.x >> 6;
    int lane = threadIdx.x & 63;
    int quad = lane >> 4;
    int m    = lane & 15;

    int n0 = blockIdx.x * 64 + wid * 16;   // first node of this wave's tile
    int n  = n0 + m;
    int nc = (n < N_NODES) ? n : (N_NODES - 1);  // clamp loads; stores guarded

    // bias per o-tile (col index in epilogue == m)
    float bias[4];
    #pragma unroll
    for (int ot = 0; ot < 4; ++ot) {
        int o = ot * 16 + m;
        if (f32) bias[ot] = ((const float*)bl)[o] + ((const float*)bs)[o];
        else     bias[ot] = bflo((uint32_t)((const uint16_t*)bl)[o])
                          + bflo((uint32_t)((const uint16_t*)bs)[o]);
    }

    f32x4 acc[4];
    #pragma unroll
    for (int ot = 0; ot < 4; ++ot) acc[ot] = (f32x4){0.f, 0.f, 0.f, 0.f};

    #pragma unroll
    for (int kk = 0; kk < N_KK; ++kk) {
        bf16x8 a;
        if (kk < 8) {
            const float* base = num + (size_t)nc * 256 + kk * 32 + quad * 8;
            float4 v0 = *(const float4*)base;
            float4 v1 = *(const float4*)(base + 4);
            float inv = 1.0f / (den[(size_t)nc * N_REL + kk] + EPS);
            a[0] = (short)f2bf(v0.x * inv); a[1] = (short)f2bf(v0.y * inv);
            a[2] = (short)f2bf(v0.z * inv); a[3] = (short)f2bf(v0.w * inv);
            a[4] = (short)f2bf(v1.x * inv); a[5] = (short)f2bf(v1.y * inv);
            a[6] = (short)f2bf(v1.z * inv); a[7] = (short)f2bf(v1.w * inv);
        } else {
            if (f32) {
                const float* base = (const float*)x + (size_t)nc * IN_DIM + quad * 8;
                float4 v0 = *(const float4*)base;
                float4 v1 = *(const float4*)(base + 4);
                a[0] = (short)f2bf(v0.x); a[1] = (short)f2bf(v0.y);
                a[2] = (short)f2bf(v0.z); a[3] = (short)f2bf(v0.w);
                a[4] = (short)f2bf(v1.x); a[5] = (short)f2bf(v1.y);
                a[6] = (short)f2bf(v1.z); a[7] = (short)f2bf(v1.w);
            } else {
                const uint16_t* base = (const uint16_t*)x + (size_t)nc * IN_DIM + quad * 8;
                a = *(const bf16x8*)base;
            }
        }
        #pragma unroll
        for (int ot = 0; ot < 4; ++ot) {
            bf16x8 b = *(const bf16x8*)(sB + ((kk * 4 + ot) * 64 + lane) * 8);
            acc[ot] = __builtin_amdgcn_mfma_f32_16x16x32_bf16(a, b, acc[ot], 0, 0, 0);
        }
    }

    // ---- epilogue: bias + relu + store ----
    #pragma unroll
    for (int ot = 0; ot < 4; ++ot) {
        #pragma unroll
        for (int reg = 0; reg < 4; ++reg) {
            int node = n0 + quad * 4 + reg;
            if (node >= N_NODES) continue;
            int o = ot * 16 + m;
            float v = fmaxf(acc[ot][reg] + bias[ot], 0.0f);
            if (f32) ((float*)out)[(size_t)node * OUT_DIM + o] = v;
            else     ((uint16_t*)out)[(size_t)node * OUT_DIM + o] = f2bf(v);
        }
    }
}

// ===========================================================================
extern "C" void kernel_launch(void* const* d_in, const int* in_sizes, int n_in,
                              void* d_out, int out_size, void* d_ws, size_t ws_size,
                              hipStream_t stream) {
    const void* x  = d_in[0];
    const int* el  = (const int*)d_in[1];
    const void* ew = d_in[2];
    const void* Wl = d_in[3];
    const void* bl = d_in[4];
    const void* Ws = d_in[5];
    const void* bs = d_in[6];

    const size_t DEN_ELEMS = (size_t)N_NODES * N_REL;            // 0.8M
    const size_t NUM_ELEMS = (size_t)N_NODES * N_REL * IN_DIM;   // 25.6M
    const size_t REQ = 64 + (DEN_ELEMS + NUM_ELEMS) * sizeof(float); // ~105.6MB
    if (ws_size < REQ) return; // round-4 evidence: ws >= REQ (Path A dispatched)

    int*   flag = (int*)d_ws;
    float* den  = (float*)((char*)d_ws + 64);
    float* num  = den + DEN_ELEMS;

    hipMemsetAsync(d_ws, 0, REQ, stream);
    detect_kernel<<<1, 256, 0, stream>>>((const uint32_t*)x, flag);
    {
        long long threads = (long long)N_EDGES * 32;
        int blocks = (int)((threads + 255) / 256);
        scatter_kernel<<<blocks, 256, 0, stream>>>(el, ew, x, flag, num, den);
    }
    {
        int blocks = (N_NODES + 63) / 64; // 1563
        dense_mfma_kernel<<<blocks, 256, 0, stream>>>(num, den, x, Wl, bl, Ws, bs, flag, d_out);
    }
}